// Round 10
// baseline (18336.320 us; speedup 1.0000x reference)
//
#include <hip/hip_runtime.h>
#include <stdint.h>

typedef uint16_t u16;
typedef __attribute__((ext_vector_type(8))) short bf16x8;   // 8 bf16 in 4 VGPRs
typedef __attribute__((ext_vector_type(4))) float f32x4;
typedef __attribute__((ext_vector_type(4))) unsigned u32x4;

#define DEVI __device__ __forceinline__

DEVI u16 f2b(float f) {                       // f32 -> bf16 RNE
  uint32_t u = __float_as_uint(f);
  uint32_t r = (u + 0x7fffu + ((u >> 16) & 1u)) >> 16;
  return (u16)r;
}
DEVI float b2f(u16 h) { return __uint_as_float(((uint32_t)h) << 16); }

typedef const __attribute__((address_space(1))) uint32_t* gptr_t;
typedef __attribute__((address_space(3))) uint32_t* lptr_t;
DEVI void gload_lds16(const void* g, void* l) {
  __builtin_amdgcn_global_load_lds((gptr_t)g, (lptr_t)l, 16, 0, 0);
}

// L2-bypass (coherent-at-L3) accessors for cross-XCD exchange. PROVEN (R3/R4/R8/R9).
DEVI bf16x8 ld_cc16(const u16* p) {
  bf16x8 r;
  asm volatile("global_load_dwordx4 %0, %1, off sc0 sc1" : "=v"(r) : "v"(p));
  return r;   // caller must s_waitcnt vmcnt(0) + sched_barrier before use
}
DEVI unsigned ld_g16(const u16* p) {          // plain cached 2B load (gx)
  unsigned r;
  asm volatile("global_load_ushort %0, %1, off" : "=v"(r) : "v"(p));
  return r;
}
DEVI void st_cc2(u16* p, u16 v) {
  uint32_t d = v;
  asm volatile("global_store_short %0, %1, off sc0 sc1" :: "v"(p), "v"(d) : "memory");
}
DEVI void st_cc4(unsigned* p, unsigned v) {
  asm volatile("global_store_dword %0, %1, off sc0 sc1" :: "v"(p), "v"(v) : "memory");
}
DEVI void st_y16(u16* p, u16 v) {
  uint32_t d = v;
  asm volatile("global_store_short %0, %1, off" :: "v"(p), "v"(d) : "memory");
}
DEVI void st_y32(float* p, float v) {
  asm volatile("global_store_dword %0, %1, off" :: "v"(p), "v"(v) : "memory");
}

// ---------------------------------------------------------------- converts
__global__ void cvt_f32_bf16(const float* __restrict__ in, u16* __restrict__ out, long n) {
  long i = ((long)blockIdx.x * blockDim.x + threadIdx.x) * 4;
  long stride = (long)gridDim.x * blockDim.x * 4;
  for (; i < n; i += stride) {
    float4 v = *(const float4*)(in + i);
    ushort4 o;
    o.x = f2b(v.x); o.y = f2b(v.y); o.z = f2b(v.z); o.w = f2b(v.w);
    *(ushort4*)(out + i) = o;
  }
}

// ---------------------------------------------------------------- GEMM (unchanged)
__global__ __launch_bounds__(256) void gemm_bt_bias(
    const u16* __restrict__ A, const u16* __restrict__ W,
    const float* __restrict__ bias, u16* __restrict__ C, int K) {
  constexpr int NLD = 6144;
  __shared__ u16 As[128 * 64];
  __shared__ u16 Bs[128 * 64];
  const int t = threadIdx.x;
  const int l = t & 63, w = t >> 6;
  const int lr = l & 15, lk = l >> 4;
  const long bm = (long)blockIdx.y * 128;
  const long bn = (long)blockIdx.x * 128;
  const int wm = (w >> 1) * 64, wn = (w & 1) * 64;

  f32x4 acc[4][4] = {};

  for (int k0 = 0; k0 < K; k0 += 64) {
    __syncthreads();
    #pragma unroll
    for (int i = 0; i < 4; ++i) {
      int slot = i * 256 + t;
      int row = slot >> 3, s = slot & 7;
      int c8 = (s ^ (row & 7)) * 8;
      char* la = (char*)As + (size_t)(i * 256 + w * 64) * 16;
      char* lb = (char*)Bs + (size_t)(i * 256 + w * 64) * 16;
      gload_lds16(A + (bm + row) * K + k0 + c8, la);
      gload_lds16(W + (bn + row) * K + k0 + c8, lb);
    }
    asm volatile("s_waitcnt vmcnt(0)" ::: "memory");
    __syncthreads();
    #pragma unroll
    for (int kk = 0; kk < 2; ++kk) {
      bf16x8 af[4], bfr[4];
      #pragma unroll
      for (int mi = 0; mi < 4; ++mi) {
        int row = wm + mi * 16 + lr;
        int sl = (kk * 4 + lk) ^ (row & 7);
        af[mi] = *(const bf16x8*)((const char*)As + row * 128 + sl * 16);
      }
      #pragma unroll
      for (int ni = 0; ni < 4; ++ni) {
        int row = wn + ni * 16 + lr;
        int sl = (kk * 4 + lk) ^ (row & 7);
        bfr[ni] = *(const bf16x8*)((const char*)Bs + row * 128 + sl * 16);
      }
      #pragma unroll
      for (int mi = 0; mi < 4; ++mi)
        #pragma unroll
        for (int ni = 0; ni < 4; ++ni)
          acc[mi][ni] = __builtin_amdgcn_mfma_f32_16x16x32_bf16(af[mi], bfr[ni], acc[mi][ni], 0, 0, 0);
    }
  }

  float bv[4];
  #pragma unroll
  for (int ni = 0; ni < 4; ++ni) bv[ni] = bias[bn + wn + ni * 16 + lr];
  #pragma unroll
  for (int mi = 0; mi < 4; ++mi)
    #pragma unroll
    for (int ni = 0; ni < 4; ++ni) {
      long col = bn + wn + ni * 16 + lr;
      #pragma unroll
      for (int j = 0; j < 4; ++j) {
        long row = bm + wm + mi * 16 + lk * 4 + j;
        C[row * NLD + col] = f2b(acc[mi][ni][j] + bv[ni]);
      }
    }
}

// ---------------------------------------------------------------- slot barrier
// 256 slots per domain (one per wave: m*8+w2). Store-only monotone stamps
// (sc0sc1). One poll iteration covers all 256 slots: 64 lanes x dwordx4.
DEVI void poll_all(const unsigned* slots, unsigned tgt, int l) {
  const unsigned* pp = slots + l * 4;
  for (;;) {
    u32x4 v;
    asm volatile("global_load_dwordx4 %0, %1, off sc0 sc1" : "=v"(v) : "v"(pp));
    asm volatile("s_waitcnt vmcnt(0)" ::: "memory");
    int ok = (v.x >= tgt && v.y >= tgt && v.z >= tgt && v.w >= tgt);
    if (__all(ok)) break;
    __builtin_amdgcn_s_sleep(1);
  }
}

// ---------------------------------------------------------------- persistent GRU layer
// 256 WGs x 512 thr (8 waves, 1 WG/CU). WG: domain dmn=bid&7 (dir=dmn>>2,
// rowgroup rg=dmn&3 -> 16 batch rows), col-tile m=bid>>3 (32 cols). Domain =
// 32 WGs exchanging h via sc0sc1 (L3-coherent, PROVEN). Per-wave stamps: each
// wave stamps after its own publish drain (no tid0 serialization, ONE
// syncthreads/step). Weights parked in 96 AGPRs, builtin MFMA.
__global__ __launch_bounds__(512, 2) void gru_layer(
    u16* __restrict__ hbA, u16* __restrict__ hbB,
    const u16* __restrict__ Whh,   // [2,3072,1024] bf16 (this layer)
    const float* __restrict__ bhh, // [2,3072] f32
    const u16* __restrict__ gx,    // [32768,6144] bf16
    u16* __restrict__ y_b, float* __restrict__ y_f,   // one non-null
    const float* __restrict__ h0l, // [2,64,1024] f32 (this layer)
    unsigned* bar) {
  __shared__ float lds[8 * 64 * 13];

  const int bid = blockIdx.x;
  const int dmn = bid & 7, m = bid >> 3;
  const int dir = dmn >> 2, rg = dmn & 3;
  const int tid = threadIdx.x;
  const int w2 = tid >> 6, l = tid & 63;
  const int lr = l & 15, lk = l >> 4;
  const int ch = w2 & 1, kh = w2 >> 1;

  unsigned* slots = bar + dmn * 256;          // 256 stamps per domain
  unsigned* myslot = slots + m * 8 + w2;

  // ---- finish-lane constants + h0 init
  const int fcol5 = tid & 31, frow = tid >> 5;      // 32 cols x 16 rows
  const int colg = m * 32 + fcol5;
  const int growd = rg * 16 + frow;
  const float bhr = bhh[dir * 3072 + colg];
  const float bhz = bhh[dir * 3072 + 1024 + colg];
  const float bhn = bhh[dir * 3072 + 2048 + colg];
  const size_t hoff = (size_t)(dir * 64 + growd) * 1024 + colg;
  float hp = h0l[hoff];
  st_cc2(hbA + hoff, f2b(hp));                // visible at L3 to all XCDs

  // ---- weights -> AGPRs (3 gates x 16 cols x 256 K per wave = 96 AGPRs)
  const u16* wb = Whh + ((size_t)(dir * 3072 + m * 32 + ch * 16 + lr)) * 1024 + kh * 256 + lk * 8;
  asm volatile("" : "+v"(wb));
  bf16x8 wr[8], wz[8], wn[8];
  #pragma unroll
  for (int kk = 0; kk < 8; ++kk) {
    wr[kk] = *(const bf16x8*)(wb + kk * 32);
    wz[kk] = *(const bf16x8*)(wb + 1024 * 1024 + kk * 32);
    wn[kk] = *(const bf16x8*)(wb + 2048 * 1024 + kk * 32);
  }
  #pragma unroll
  for (int kk = 0; kk < 8; ++kk)
    asm volatile("" : "+a"(wr[kk]), "+a"(wz[kk]), "+a"(wn[kk]));

  // ---- loop state
  const int tt0 = dir ? 511 : 0;
  long gxp = (long)(tt0 * 64 + growd) * 6144 + (long)dir * 3072 + colg;
  const long gxstep = dir ? -(64 * 6144) : (64 * 6144);
  long yp = (long)(tt0 * 64 + growd) * 2048 + (long)dir * 1024 + colg;
  const long ystep = dir ? -(64 * 2048) : (64 * 2048);

  const u16* apA = hbA + (size_t)(dir * 64 + rg * 16 + lr) * 1024 + kh * 256 + lk * 8;
  const u16* apB = hbB + (size_t)(dir * 64 + rg * 16 + lr) * 1024 + kh * 256 + lk * 8;

  const int lf = ((frow >> 2) << 4) | (fcol5 & 15);  // source lane in compute wave
  const int jj = frow & 3;                           // acc reg index
  const int chf = fcol5 >> 4;                        // source col-half

  // ---- init: own h0 publish drained (per wave), then per-wave stamp
  asm volatile("s_waitcnt vmcnt(0)" ::: "memory");
  if (l == 0) st_cc4(myslot, 1u);

  for (int t = 0; t < 512; ++t) {
    // ---- wait for domain step-readiness (all 256 wave-stamps >= t+1)
    poll_all(slots, (unsigned)(t + 1), l);

    const u16* ap = (t & 1) ? apB : apA;
    u16* hb_out = (t & 1) ? hbA : hbB;

    // ---- issue h loads (sc0sc1) + this step's gx loads (plain); one wait
    bf16x8 av[8];
    #pragma unroll
    for (int kk = 0; kk < 8; ++kk) av[kk] = ld_cc16(ap + kk * 32);
    unsigned gr = ld_g16(gx + gxp);
    unsigned gz = ld_g16(gx + gxp + 1024);
    unsigned gn = ld_g16(gx + gxp + 2048);
    asm volatile("s_waitcnt vmcnt(0)" ::: "memory");
    __builtin_amdgcn_sched_barrier(0);

    // ---- 24 MFMAs: 3 gate chains over this wave's K-quarter
    f32x4 aR = {0.f,0.f,0.f,0.f}, aZ = {0.f,0.f,0.f,0.f}, aN = {0.f,0.f,0.f,0.f};
    #pragma unroll
    for (int kk = 0; kk < 8; ++kk) {
      aR = __builtin_amdgcn_mfma_f32_16x16x32_bf16(av[kk], wr[kk], aR, 0, 0, 0);
      aZ = __builtin_amdgcn_mfma_f32_16x16x32_bf16(av[kk], wz[kk], aZ, 0, 0, 0);
      aN = __builtin_amdgcn_mfma_f32_16x16x32_bf16(av[kk], wn[kk], aN, 0, 0, 0);
    }
    float* myl = lds + (size_t)(w2 * 64 + l) * 13;
    #pragma unroll
    for (int j = 0; j < 4; ++j) { myl[j] = aR[j]; myl[4 + j] = aZ[j]; myl[8 + j] = aN[j]; }
    __syncthreads();

    // ---- finish: combine 4 K-quarter partials, gate math, publish
    float ghr = 0.f, ghz = 0.f, ghn = 0.f;
    #pragma unroll
    for (int k2 = 0; k2 < 4; ++k2) {
      const float* pl = lds + (size_t)((k2 * 2 + chf) * 64 + lf) * 13;
      ghr += pl[jj]; ghz += pl[4 + jj]; ghn += pl[8 + jj];
    }
    float rgt = 1.f / (1.f + __expf(-(b2f((u16)gr) + ghr + bhr)));
    float zgt = 1.f / (1.f + __expf(-(b2f((u16)gz) + ghz + bhz)));
    float ngt = tanhf(b2f((u16)gn) + rgt * (ghn + bhn));
    hp = (1.f - zgt) * ngt + zgt * hp;
    st_cc2(hb_out + hoff, f2b(hp));
    if (y_b) st_y16(y_b + yp, f2b(hp));
    else     st_y32(y_f + yp, hp);
    gxp += gxstep; yp += ystep;

    // ---- own publish drained -> own wave stamp (no WG-wide sync needed:
    // LDS reads done in program order; others gate on ALL 256 stamps)
    asm volatile("s_waitcnt vmcnt(0)" ::: "memory");
    if (l == 0) st_cc4(myslot, (unsigned)(t + 2));
  }
}

// ---------------------------------------------------------------- launch
extern "C" void kernel_launch(void* const* d_in, const int* in_sizes, int n_in,
                              void* d_out, int out_size, void* d_ws, size_t ws_size,
                              hipStream_t stream) {
  (void)in_sizes; (void)n_in; (void)out_size; (void)ws_size;
  const float* x     = (const float*)d_in[0];   // [512,64,1024]
  const float* h0    = (const float*)d_in[1];   // [6,64,1024]
  const float* w_ih0 = (const float*)d_in[2];   // [2,3072,1024]
  const float* w_ih  = (const float*)d_in[3];   // [2,2,3072,2048]
  const float* w_hh  = (const float*)d_in[4];   // [3,2,3072,1024]
  const float* b_ih  = (const float*)d_in[5];   // [3,2,3072]
  const float* b_hh  = (const float*)d_in[6];   // [3,2,3072]
  float* out = (float*)d_out;                   // [512,64,2048]

  char* p = (char*)d_ws;
  u16* wA    = (u16*)p; p += (size_t)32768 * 2048 * 2;       // layer input bf16
  u16* wGx   = (u16*)p; p += (size_t)32768 * 6144 * 2;       // gate preacts bf16
  u16* wWih0 = (u16*)p; p += (size_t)6144 * 1024 * 2;
  u16* wWih  = (u16*)p; p += (size_t)2 * 6144 * 2048 * 2;
  u16* wWhh  = (u16*)p; p += (size_t)6 * 3072 * 1024 * 2;
  u16* wHb0  = (u16*)p; p += (size_t)2 * 64 * 1024 * 2;
  u16* wHb1  = (u16*)p; p += (size_t)2 * 64 * 1024 * 2;
  unsigned* wBar = (unsigned*)p; p += 4096 * 4;

  cvt_f32_bf16<<<2048, 256, 0, stream>>>(x,     wA,    (long)33554432);
  cvt_f32_bf16<<<2048, 256, 0, stream>>>(w_ih0, wWih0, (long)6291456);
  cvt_f32_bf16<<<2048, 256, 0, stream>>>(w_ih,  wWih,  (long)25165824);
  cvt_f32_bf16<<<2048, 256, 0, stream>>>(w_hh,  wWhh,  (long)18874368);

  for (int layer = 0; layer < 3; ++layer) {
    int K = (layer == 0) ? 1024 : 2048;
    const u16* Wg = (layer == 0) ? wWih0 : (wWih + (size_t)(layer - 1) * 6144 * 2048);
    gemm_bt_bias<<<dim3(48, 256), 256, 0, stream>>>(wA, Wg, b_ih + (size_t)layer * 6144, wGx, K);

    hipMemsetAsync(wBar, 0, 4096 * 4, stream);

    const u16* Whh_l   = wWhh + (size_t)layer * 2 * 3072 * 1024;
    const float* bhh_l = b_hh + (size_t)layer * 6144;
    const float* h0_l  = h0 + (size_t)layer * 131072;
    u16*   yb = (layer < 2) ? wA : nullptr;
    float* yf = (layer < 2) ? nullptr : out;
    gru_layer<<<256, 512, 0, stream>>>(wHb0, wHb1, Whh_l, bhh_l, wGx, yb, yf, h0_l, wBar);
  }
}

// Round 13
// 14725.130 us; speedup vs baseline: 1.2452x; 1.2452x over previous
//
#include <hip/hip_runtime.h>
#include <stdint.h>

typedef uint16_t u16;
typedef __attribute__((ext_vector_type(8))) short bf16x8;   // 8 bf16 in 4 VGPRs
typedef __attribute__((ext_vector_type(4))) float f32x4;
typedef __attribute__((ext_vector_type(4))) unsigned u32x4;

#define DEVI __device__ __forceinline__

DEVI u16 f2b(float f) {                       // f32 -> bf16 RNE
  uint32_t u = __float_as_uint(f);
  uint32_t r = (u + 0x7fffu + ((u >> 16) & 1u)) >> 16;
  return (u16)r;
}
DEVI float b2f(u16 h) { return __uint_as_float(((uint32_t)h) << 16); }

typedef const __attribute__((address_space(1))) uint32_t* gptr_t;
typedef __attribute__((address_space(3))) uint32_t* lptr_t;
DEVI void gload_lds16(const void* g, void* l) {
  __builtin_amdgcn_global_load_lds((gptr_t)g, (lptr_t)l, 16, 0, 0);
}

// L3-coherent accessors (sc0 sc1) — the PROVEN cross-XCD path (R3/R4/R8/R9).
DEVI u32x4 ld_cc4x(const unsigned* p) {
  u32x4 r;
  asm volatile("global_load_dwordx4 %0, %1, off sc0 sc1" : "=v"(r) : "v"(p));
  return r;   // caller: s_waitcnt vmcnt(0) + sched_barrier(0) before use (rule #18)
}
DEVI void st_cc4(unsigned* p, unsigned v) {
  asm volatile("global_store_dword %0, %1, off sc0 sc1" :: "v"(p), "v"(v) : "memory");
}
DEVI void st_y16(u16* p, u16 v) {
  uint32_t d = v;
  asm volatile("global_store_short %0, %1, off" :: "v"(p), "v"(d) : "memory");
}
DEVI void st_y32(float* p, float v) {
  asm volatile("global_store_dword %0, %1, off" :: "v"(p), "v"(v) : "memory");
}

// pack 8 tagged u32 (low16 = bf16) into one bf16x8 fragment
DEVI bf16x8 pack8(u32x4 lo, u32x4 hi) {
  union { bf16x8 v; unsigned u[4]; } r;
  r.u[0] = (lo.x & 0xFFFFu) | (lo.y << 16);
  r.u[1] = (lo.z & 0xFFFFu) | (lo.w << 16);
  r.u[2] = (hi.x & 0xFFFFu) | (hi.y << 16);
  r.u[3] = (hi.z & 0xFFFFu) | (hi.w << 16);
  return r.v;
}

// ---------------------------------------------------------------- converts
__global__ void cvt_f32_bf16(const float* __restrict__ in, u16* __restrict__ out, long n) {
  long i = ((long)blockIdx.x * blockDim.x + threadIdx.x) * 4;
  long stride = (long)gridDim.x * blockDim.x * 4;
  for (; i < n; i += stride) {
    float4 v = *(const float4*)(in + i);
    ushort4 o;
    o.x = f2b(v.x); o.y = f2b(v.y); o.z = f2b(v.z); o.w = f2b(v.w);
    *(ushort4*)(out + i) = o;
  }
}

// ---------------------------------------------------------------- GEMM (unchanged)
__global__ __launch_bounds__(256) void gemm_bt_bias(
    const u16* __restrict__ A, const u16* __restrict__ W,
    const float* __restrict__ bias, u16* __restrict__ C, int K) {
  constexpr int NLD = 6144;
  __shared__ u16 As[128 * 64];
  __shared__ u16 Bs[128 * 64];
  const int t = threadIdx.x;
  const int l = t & 63, w = t >> 6;
  const int lr = l & 15, lk = l >> 4;
  const long bm = (long)blockIdx.y * 128;
  const long bn = (long)blockIdx.x * 128;
  const int wm = (w >> 1) * 64, wn = (w & 1) * 64;

  f32x4 acc[4][4] = {};

  for (int k0 = 0; k0 < K; k0 += 64) {
    __syncthreads();
    #pragma unroll
    for (int i = 0; i < 4; ++i) {
      int slot = i * 256 + t;
      int row = slot >> 3, s = slot & 7;
      int c8 = (s ^ (row & 7)) * 8;
      char* la = (char*)As + (size_t)(i * 256 + w * 64) * 16;
      char* lb = (char*)Bs + (size_t)(i * 256 + w * 64) * 16;
      gload_lds16(A + (bm + row) * K + k0 + c8, la);
      gload_lds16(W + (bn + row) * K + k0 + c8, lb);
    }
    asm volatile("s_waitcnt vmcnt(0)" ::: "memory");
    __syncthreads();
    #pragma unroll
    for (int kk = 0; kk < 2; ++kk) {
      bf16x8 af[4], bfr[4];
      #pragma unroll
      for (int mi = 0; mi < 4; ++mi) {
        int row = wm + mi * 16 + lr;
        int sl = (kk * 4 + lk) ^ (row & 7);
        af[mi] = *(const bf16x8*)((const char*)As + row * 128 + sl * 16);
      }
      #pragma unroll
      for (int ni = 0; ni < 4; ++ni) {
        int row = wn + ni * 16 + lr;
        int sl = (kk * 4 + lk) ^ (row & 7);
        bfr[ni] = *(const bf16x8*)((const char*)Bs + row * 128 + sl * 16);
      }
      #pragma unroll
      for (int mi = 0; mi < 4; ++mi)
        #pragma unroll
        for (int ni = 0; ni < 4; ++ni)
          acc[mi][ni] = __builtin_amdgcn_mfma_f32_16x16x32_bf16(af[mi], bfr[ni], acc[mi][ni], 0, 0, 0);
    }
  }

  float bv[4];
  #pragma unroll
  for (int ni = 0; ni < 4; ++ni) bv[ni] = bias[bn + wn + ni * 16 + lr];
  #pragma unroll
  for (int mi = 0; mi < 4; ++mi)
    #pragma unroll
    for (int ni = 0; ni < 4; ++ni) {
      long col = bn + wn + ni * 16 + lr;
      #pragma unroll
      for (int j = 0; j < 4; ++j) {
        long row = bm + wm + mi * 16 + lk * 4 + j;
        C[row * NLD + col] = f2b(acc[mi][ni][j] + bv[ni]);
      }
    }
}

// ---------------------------------------------------------------- persistent GRU layer
// DATA-EMBEDDED EPOCHS (R12 design + rule-#18 fixes): h state = u32
// (tag<<16)|bf16 in two parity buffers. Readers poll exactly the words they
// consume (sc0sc1) until all tags == base+t+1; the final sweep IS the h-load.
// Geometry = PROVEN R9: 256 WGs x 512 thr; dmn=bid&7 (dir,rg->16 rows),
// m=bid>>3 (32 cols). Waves: ch=w2&1, kh=w2>>1 (K-quarter). 96 AGPR weights.
__global__ __launch_bounds__(512, 2) void gru_layer(
    unsigned* __restrict__ h32A, unsigned* __restrict__ h32B,
    const u16* __restrict__ Whh,   // [2,3072,1024] bf16 (this layer)
    const float* __restrict__ bhh, // [2,3072] f32
    const u16* __restrict__ gx,    // [32768,6144] bf16
    u16* __restrict__ y_b, float* __restrict__ y_f,   // one non-null
    const float* __restrict__ h0l, // [2,64,1024] f32 (this layer)
    unsigned base) {               // layer-unique tag base
  __shared__ float lds[8 * 64 * 13];

  const int bid = blockIdx.x;
  const int dmn = bid & 7, m = bid >> 3;
  const int dir = dmn >> 2, rg = dmn & 3;
  const int tid = threadIdx.x;
  const int w2 = tid >> 6, l = tid & 63;
  const int lr = l & 15, lk = l >> 4;
  const int ch = w2 & 1, kh = w2 >> 1;

  // ---- finish-lane constants + h0 publish (tag base+1 into A)
  const int fcol5 = tid & 31, frow = tid >> 5;      // 32 cols x 16 rows
  const int colg = m * 32 + fcol5;
  const int growd = rg * 16 + frow;
  const float bhr = bhh[dir * 3072 + colg];
  const float bhz = bhh[dir * 3072 + 1024 + colg];
  const float bhn = bhh[dir * 3072 + 2048 + colg];
  const size_t hoff = (size_t)(dir * 64 + growd) * 1024 + colg;
  float hp = h0l[hoff];
  st_cc4(h32A + hoff, ((base + 1u) << 16) | f2b(hp));

  // ---- weights -> AGPRs (3 gates x 16 cols x 256 K per wave = 96 AGPRs)
  const u16* wb = Whh + ((size_t)(dir * 3072 + m * 32 + ch * 16 + lr)) * 1024 + kh * 256 + lk * 8;
  asm volatile("" : "+v"(wb));
  bf16x8 wr[8], wz[8], wn[8];
  #pragma unroll
  for (int kk = 0; kk < 8; ++kk) {
    wr[kk] = *(const bf16x8*)(wb + kk * 32);
    wz[kk] = *(const bf16x8*)(wb + 1024 * 1024 + kk * 32);
    wn[kk] = *(const bf16x8*)(wb + 2048 * 1024 + kk * 32);
  }
  #pragma unroll
  for (int kk = 0; kk < 8; ++kk)
    asm volatile("" : "+a"(wr[kk]), "+a"(wz[kk]), "+a"(wn[kk]));

  // ---- loop state
  const int tt0 = dir ? 511 : 0;
  long gxp = (long)(tt0 * 64 + growd) * 6144 + (long)dir * 3072 + colg;
  const long gxstep = dir ? -(64 * 6144) : (64 * 6144);
  long yp = (long)(tt0 * 64 + growd) * 2048 + (long)dir * 1024 + colg;
  const long ystep = dir ? -(64 * 2048) : (64 * 2048);

  const unsigned* rdA = h32A + (size_t)(dir * 64 + rg * 16 + lr) * 1024 + kh * 256 + lk * 8;
  const unsigned* rdB = h32B + (size_t)(dir * 64 + rg * 16 + lr) * 1024 + kh * 256 + lk * 8;

  const int lf = ((frow >> 2) << 4) | (fcol5 & 15);  // source lane in compute wave
  const int jj = frow & 3;                           // acc reg index
  const int chf = fcol5 >> 4;                        // source col-half

  // gx prefetch for t=0 — PLAIN C loads (compiler-managed waits; R9-proven)
  u16 gcr = gx[gxp], gcz = gx[gxp + 1024], gcn = gx[gxp + 2048];

  for (int t = 0; t < 512; ++t) {
    const unsigned* rd = (t & 1) ? rdB : rdA;       // h(t-1): tags base+t+1
    unsigned* wrb = (t & 1) ? h32A : h32B;          // h(t): tags base+t+2
    const unsigned want = base + (unsigned)t + 1u;

    // ---- poll+load+repack, two halves of the K-quarter (caps VGPR pressure)
    bf16x8 av[8];
    #pragma unroll
    for (int half = 0; half < 2; ++half) {
      u32x4 lo[4], hi[4];
      for (;;) {
        #pragma unroll
        for (int q = 0; q < 4; ++q) {
          lo[q] = ld_cc4x(rd + (half * 4 + q) * 32);
          hi[q] = ld_cc4x(rd + (half * 4 + q) * 32 + 4);
        }
        asm volatile("s_waitcnt vmcnt(0)" ::: "memory");
        __builtin_amdgcn_sched_barrier(0);          // rule #18: fence VALU checks
        unsigned ok = 1u;
        #pragma unroll
        for (int q = 0; q < 4; ++q) {
          ok &= (unsigned)((lo[q].x >> 16) == want) & (unsigned)((lo[q].y >> 16) == want)
              & (unsigned)((lo[q].z >> 16) == want) & (unsigned)((lo[q].w >> 16) == want)
              & (unsigned)((hi[q].x >> 16) == want) & (unsigned)((hi[q].y >> 16) == want)
              & (unsigned)((hi[q].z >> 16) == want) & (unsigned)((hi[q].w >> 16) == want);
        }
        if (__all((int)ok)) break;
        __builtin_amdgcn_s_sleep(2);
      }
      #pragma unroll
      for (int q = 0; q < 4; ++q) av[half * 4 + q] = pack8(lo[q], hi[q]);
    }

    // ---- 24 MFMAs: 3 gate chains over this wave's K-quarter
    f32x4 aR = {0.f,0.f,0.f,0.f}, aZ = {0.f,0.f,0.f,0.f}, aN = {0.f,0.f,0.f,0.f};
    #pragma unroll
    for (int kk = 0; kk < 8; ++kk) {
      aR = __builtin_amdgcn_mfma_f32_16x16x32_bf16(av[kk], wr[kk], aR, 0, 0, 0);
      aZ = __builtin_amdgcn_mfma_f32_16x16x32_bf16(av[kk], wz[kk], aZ, 0, 0, 0);
      aN = __builtin_amdgcn_mfma_f32_16x16x32_bf16(av[kk], wn[kk], aN, 0, 0, 0);
    }
    __syncthreads();          // all own waves passed polls; prev combine-reads done
    float* myl = lds + (size_t)(w2 * 64 + l) * 13;
    #pragma unroll
    for (int j = 0; j < 4; ++j) { myl[j] = aR[j]; myl[4 + j] = aZ[j]; myl[8 + j] = aN[j]; }
    __syncthreads();

    // ---- finish: combine 4 K-quarter partials, gate math, tagged publish
    float ghr = 0.f, ghz = 0.f, ghn = 0.f;
    #pragma unroll
    for (int k2 = 0; k2 < 4; ++k2) {
      const float* pl = lds + (size_t)((k2 * 2 + chf) * 64 + lf) * 13;
      ghr += pl[jj]; ghz += pl[4 + jj]; ghn += pl[8 + jj];
    }
    float rgt = 1.f / (1.f + __expf(-(b2f(gcr) + ghr + bhr)));
    float zgt = 1.f / (1.f + __expf(-(b2f(gcz) + ghz + bhz)));
    float ngt = tanhf(b2f(gcn) + rgt * (ghn + bhn));
    hp = (1.f - zgt) * ngt + zgt * hp;
    st_cc4(wrb + hoff, ((base + (unsigned)t + 2u) << 16) | f2b(hp));
    if (y_b) st_y16(y_b + yp, f2b(hp));
    else     st_y32(y_f + yp, hp);

    // ---- next-step gx prefetch (plain C loads; compiler inserts waits)
    long gxn_p = gxp + gxstep;                 // t=511 value unused
    if (t < 511) {
      gcr = gx[gxn_p]; gcz = gx[gxn_p + 1024]; gcn = gx[gxn_p + 2048];
    }
    gxp = gxn_p; yp += ystep;
  }
}

// ---------------------------------------------------------------- launch
extern "C" void kernel_launch(void* const* d_in, const int* in_sizes, int n_in,
                              void* d_out, int out_size, void* d_ws, size_t ws_size,
                              hipStream_t stream) {
  (void)in_sizes; (void)n_in; (void)out_size; (void)ws_size;
  const float* x     = (const float*)d_in[0];   // [512,64,1024]
  const float* h0    = (const float*)d_in[1];   // [6,64,1024]
  const float* w_ih0 = (const float*)d_in[2];   // [2,3072,1024]
  const float* w_ih  = (const float*)d_in[3];   // [2,2,3072,2048]
  const float* w_hh  = (const float*)d_in[4];   // [3,2,3072,1024]
  const float* b_ih  = (const float*)d_in[5];   // [3,2,3072]
  const float* b_hh  = (const float*)d_in[6];   // [3,2,3072]
  float* out = (float*)d_out;                   // [512,64,2048]

  char* p = (char*)d_ws;
  u16* wA    = (u16*)p; p += (size_t)32768 * 2048 * 2;       // layer input bf16
  u16* wGx   = (u16*)p; p += (size_t)32768 * 6144 * 2;       // gate preacts bf16
  u16* wWih0 = (u16*)p; p += (size_t)6144 * 1024 * 2;
  u16* wWih  = (u16*)p; p += (size_t)2 * 6144 * 2048 * 2;
  u16* wWhh  = (u16*)p; p += (size_t)6 * 3072 * 1024 * 2;
  unsigned* h32A = (unsigned*)p; p += (size_t)2 * 64 * 1024 * 4;
  unsigned* h32B = (unsigned*)p; p += (size_t)2 * 64 * 1024 * 4;

  // clear tagged h buffers (kills stale tags from previous graph replays)
  hipMemsetAsync(h32A, 0, (size_t)2 * 64 * 1024 * 4, stream);
  hipMemsetAsync(h32B, 0, (size_t)2 * 64 * 1024 * 4, stream);

  cvt_f32_bf16<<<2048, 256, 0, stream>>>(x,     wA,    (long)33554432);
  cvt_f32_bf16<<<2048, 256, 0, stream>>>(w_ih0, wWih0, (long)6291456);
  cvt_f32_bf16<<<2048, 256, 0, stream>>>(w_ih,  wWih,  (long)25165824);
  cvt_f32_bf16<<<2048, 256, 0, stream>>>(w_hh,  wWhh,  (long)18874368);

  for (int layer = 0; layer < 3; ++layer) {
    int K = (layer == 0) ? 1024 : 2048;
    const u16* Wg = (layer == 0) ? wWih0 : (wWih + (size_t)(layer - 1) * 6144 * 2048);
    gemm_bt_bias<<<dim3(48, 256), 256, 0, stream>>>(wA, Wg, b_ih + (size_t)layer * 6144, wGx, K);

    const u16* Whh_l   = wWhh + (size_t)layer * 2 * 3072 * 1024;
    const float* bhh_l = b_hh + (size_t)layer * 6144;
    const float* h0_l  = h0 + (size_t)layer * 131072;
    u16*   yb = (layer < 2) ? wA : nullptr;
    float* yf = (layer < 2) ? nullptr : out;
    gru_layer<<<256, 512, 0, stream>>>(h32A, h32B, Whh_l, bhh_l, wGx, yb, yf, h0_l,
                                       (unsigned)(layer * 1024));
  }
}

// Round 14
// 12240.829 us; speedup vs baseline: 1.4980x; 1.2030x over previous
//
#include <hip/hip_runtime.h>
#include <stdint.h>

typedef uint16_t u16;
typedef __attribute__((ext_vector_type(8))) short bf16x8;   // 8 bf16 in 4 VGPRs
typedef __attribute__((ext_vector_type(4))) float f32x4;
typedef __attribute__((ext_vector_type(4))) unsigned u32x4;

#define DEVI __device__ __forceinline__

DEVI u16 f2b(float f) {                       // f32 -> bf16 RNE
  uint32_t u = __float_as_uint(f);
  uint32_t r = (u + 0x7fffu + ((u >> 16) & 1u)) >> 16;
  return (u16)r;
}
DEVI float b2f(u16 h) { return __uint_as_float(((uint32_t)h) << 16); }

typedef const __attribute__((address_space(1))) uint32_t* gptr_t;
typedef __attribute__((address_space(3))) uint32_t* lptr_t;
DEVI void gload_lds16(const void* g, void* l) {
  __builtin_amdgcn_global_load_lds((gptr_t)g, (lptr_t)l, 16, 0, 0);
}

// L3-coherent accessors for cross-XCD exchange. PROVEN (R3/R4/R8/R9).
DEVI bf16x8 ld_cc16(const u16* p) {
  bf16x8 r;
  asm volatile("global_load_dwordx4 %0, %1, off sc0 sc1" : "=v"(r) : "v"(p));
  return r;   // caller must s_waitcnt + sched_barrier before use
}
DEVI unsigned ld_g16(const u16* p) {          // plain cached 2B load (gx), asm
  unsigned r;
  asm volatile("global_load_ushort %0, %1, off" : "=v"(r) : "v"(p));
  return r;
}
DEVI void st_cc2(u16* p, u16 v) {
  uint32_t d = v;
  asm volatile("global_store_short %0, %1, off sc0 sc1" :: "v"(p), "v"(d) : "memory");
}
DEVI void st_cc4(unsigned* p, unsigned v) {
  asm volatile("global_store_dword %0, %1, off sc0 sc1" :: "v"(p), "v"(v) : "memory");
}
DEVI void st_y16(u16* p, u16 v) {
  uint32_t d = v;
  asm volatile("global_store_short %0, %1, off" :: "v"(p), "v"(d) : "memory");
}
DEVI void st_y32(float* p, float v) {
  asm volatile("global_store_dword %0, %1, off" :: "v"(p), "v"(v) : "memory");
}

// ---------------------------------------------------------------- converts
__global__ void cvt_f32_bf16(const float* __restrict__ in, u16* __restrict__ out, long n) {
  long i = ((long)blockIdx.x * blockDim.x + threadIdx.x) * 4;
  long stride = (long)gridDim.x * blockDim.x * 4;
  for (; i < n; i += stride) {
    float4 v = *(const float4*)(in + i);
    ushort4 o;
    o.x = f2b(v.x); o.y = f2b(v.y); o.z = f2b(v.z); o.w = f2b(v.w);
    *(ushort4*)(out + i) = o;
  }
}

// ---------------------------------------------------------------- GEMM (unchanged)
__global__ __launch_bounds__(256) void gemm_bt_bias(
    const u16* __restrict__ A, const u16* __restrict__ W,
    const float* __restrict__ bias, u16* __restrict__ C, int K) {
  constexpr int NLD = 6144;
  __shared__ u16 As[128 * 64];
  __shared__ u16 Bs[128 * 64];
  const int t = threadIdx.x;
  const int l = t & 63, w = t >> 6;
  const int lr = l & 15, lk = l >> 4;
  const long bm = (long)blockIdx.y * 128;
  const long bn = (long)blockIdx.x * 128;
  const int wm = (w >> 1) * 64, wn = (w & 1) * 64;

  f32x4 acc[4][4] = {};

  for (int k0 = 0; k0 < K; k0 += 64) {
    __syncthreads();
    #pragma unroll
    for (int i = 0; i < 4; ++i) {
      int slot = i * 256 + t;
      int row = slot >> 3, s = slot & 7;
      int c8 = (s ^ (row & 7)) * 8;
      char* la = (char*)As + (size_t)(i * 256 + w * 64) * 16;
      char* lb = (char*)Bs + (size_t)(i * 256 + w * 64) * 16;
      gload_lds16(A + (bm + row) * K + k0 + c8, la);
      gload_lds16(W + (bn + row) * K + k0 + c8, lb);
    }
    asm volatile("s_waitcnt vmcnt(0)" ::: "memory");
    __syncthreads();
    #pragma unroll
    for (int kk = 0; kk < 2; ++kk) {
      bf16x8 af[4], bfr[4];
      #pragma unroll
      for (int mi = 0; mi < 4; ++mi) {
        int row = wm + mi * 16 + lr;
        int sl = (kk * 4 + lk) ^ (row & 7);
        af[mi] = *(const bf16x8*)((const char*)As + row * 128 + sl * 16);
      }
      #pragma unroll
      for (int ni = 0; ni < 4; ++ni) {
        int row = wn + ni * 16 + lr;
        int sl = (kk * 4 + lk) ^ (row & 7);
        bfr[ni] = *(const bf16x8*)((const char*)Bs + row * 128 + sl * 16);
      }
      #pragma unroll
      for (int mi = 0; mi < 4; ++mi)
        #pragma unroll
        for (int ni = 0; ni < 4; ++ni)
          acc[mi][ni] = __builtin_amdgcn_mfma_f32_16x16x32_bf16(af[mi], bfr[ni], acc[mi][ni], 0, 0, 0);
    }
  }

  float bv[4];
  #pragma unroll
  for (int ni = 0; ni < 4; ++ni) bv[ni] = bias[bn + wn + ni * 16 + lr];
  #pragma unroll
  for (int mi = 0; mi < 4; ++mi)
    #pragma unroll
    for (int ni = 0; ni < 4; ++ni) {
      long col = bn + wn + ni * 16 + lr;
      #pragma unroll
      for (int j = 0; j < 4; ++j) {
        long row = bm + wm + mi * 16 + lk * 4 + j;
        C[row * NLD + col] = f2b(acc[mi][ni][j] + bv[ni]);
      }
    }
}

// ---------------------------------------------------------------- quarter poll
// Wave kh consumes h-cols produced only by WGs m in [kh*8, kh*8+8): poll just
// those 8 stamps (2 lanes x dwordx4). WG-level union across 8 waves = full
// domain, so the first __syncthreads preserves R9's overwrite-safety proof.
DEVI void poll_quarter(const unsigned* slots, int kh, unsigned tgt, int l) {
  const unsigned* pp = slots + kh * 8 + (l & 1) * 4;
  for (;;) {
    u32x4 v;
    asm volatile("global_load_dwordx4 %0, %1, off sc0 sc1" : "=v"(v) : "v"(pp));
    asm volatile("s_waitcnt vmcnt(0)" ::: "memory");
    int ok = (l < 2) ? (v.x >= tgt && v.y >= tgt && v.z >= tgt && v.w >= tgt) : 1;
    if (__all(ok)) break;
    __builtin_amdgcn_s_sleep(1);
  }
}

// ---------------------------------------------------------------- persistent GRU layer
// R9 structure (PROVEN 2.12 ms/layer) + two latency cuts:
//  (1) next-step gx asm loads co-issued with h loads; MFMA gated by vmcnt(3)
//      (waits the 8 OLDEST = h loads; gx lands under compute) + sched_barrier.
//  (2) quarter-scoped polling (see poll_quarter).
// 256 WGs x 512 thr; dmn=bid&7 (dir,rg->16 rows), m=bid>>3 (32 cols). Waves:
// ch=w2&1, kh=w2>>1 (K-quarter). Weights in 96 AGPRs, builtin MFMA. All
// cross-XCD exchange sc0sc1; store-only monotone stamps by tid0 after the
// drain-certifying second __syncthreads.
__global__ __launch_bounds__(512, 2) void gru_layer(
    u16* __restrict__ hbA, u16* __restrict__ hbB,
    const u16* __restrict__ Whh,   // [2,3072,1024] bf16 (this layer)
    const float* __restrict__ bhh, // [2,3072] f32
    const u16* __restrict__ gx,    // [32768,6144] bf16
    u16* __restrict__ y_b, float* __restrict__ y_f,   // one non-null
    const float* __restrict__ h0l, // [2,64,1024] f32 (this layer)
    unsigned* bar) {
  __shared__ float lds[8 * 64 * 13];

  const int bid = blockIdx.x;
  const int dmn = bid & 7, m = bid >> 3;
  const int dir = dmn >> 2, rg = dmn & 3;
  const int tid = threadIdx.x;
  const int w2 = tid >> 6, l = tid & 63;
  const int lr = l & 15, lk = l >> 4;
  const int ch = w2 & 1, kh = w2 >> 1;

  unsigned* slots = bar + dmn * 64;           // 32 stamps per domain

  // ---- finish-lane constants + h0 init
  const int fcol5 = tid & 31, frow = tid >> 5;      // 32 cols x 16 rows
  const int colg = m * 32 + fcol5;
  const int growd = rg * 16 + frow;
  const float bhr = bhh[dir * 3072 + colg];
  const float bhz = bhh[dir * 3072 + 1024 + colg];
  const float bhn = bhh[dir * 3072 + 2048 + colg];
  const size_t hoff = (size_t)(dir * 64 + growd) * 1024 + colg;
  float hp = h0l[hoff];
  st_cc2(hbA + hoff, f2b(hp));                // visible at L3 to all XCDs

  // ---- weights -> AGPRs (3 gates x 16 cols x 256 K per wave = 96 AGPRs)
  const u16* wb = Whh + ((size_t)(dir * 3072 + m * 32 + ch * 16 + lr)) * 1024 + kh * 256 + lk * 8;
  asm volatile("" : "+v"(wb));
  bf16x8 wr[8], wz[8], wn[8];
  #pragma unroll
  for (int kk = 0; kk < 8; ++kk) {
    wr[kk] = *(const bf16x8*)(wb + kk * 32);
    wz[kk] = *(const bf16x8*)(wb + 1024 * 1024 + kk * 32);
    wn[kk] = *(const bf16x8*)(wb + 2048 * 1024 + kk * 32);
  }
  #pragma unroll
  for (int kk = 0; kk < 8; ++kk)
    asm volatile("" : "+a"(wr[kk]), "+a"(wz[kk]), "+a"(wn[kk]));

  // ---- loop state
  const int tt0 = dir ? 511 : 0;
  long gxp = (long)(tt0 * 64 + growd) * 6144 + (long)dir * 3072 + colg;
  const long gxstep = dir ? -(64 * 6144) : (64 * 6144);
  long yp = (long)(tt0 * 64 + growd) * 2048 + (long)dir * 1024 + colg;
  const long ystep = dir ? -(64 * 2048) : (64 * 2048);

  const u16* apA = hbA + (size_t)(dir * 64 + rg * 16 + lr) * 1024 + kh * 256 + lk * 8;
  const u16* apB = hbB + (size_t)(dir * 64 + rg * 16 + lr) * 1024 + kh * 256 + lk * 8;

  const int lf = ((frow >> 2) << 4) | (fcol5 & 15);  // source lane in compute wave
  const int jj = frow & 3;                           // acc reg index
  const int chf = fcol5 >> 4;                        // source col-half

  // gx for t=0 (asm loads, drained by the init vmcnt(0) below)
  unsigned gcr = ld_g16(gx + gxp), gcz = ld_g16(gx + gxp + 1024), gcn = ld_g16(gx + gxp + 2048);

  asm volatile("s_waitcnt vmcnt(0)" ::: "memory");   // h0 publish + gx drained
  __syncthreads();
  if (tid == 0) st_cc4(slots + m, 1u);

  for (int t = 0; t < 512; ++t) {
    // ---- wait for THIS wave's 8 producer WGs (quarter scope)
    poll_quarter(slots, kh, (unsigned)(t + 1), l);

    const u16* ap = (t & 1) ? apB : apA;
    u16* hb_out = (t & 1) ? hbA : hbB;

    // ---- issue 8 h loads (sc0sc1) then 3 next-step gx loads (plain, asm).
    // vmcnt(3) waits the 8 OLDEST (h); gx stays in flight under compute.
    bf16x8 av[8];
    #pragma unroll
    for (int kk = 0; kk < 8; ++kk) av[kk] = ld_cc16(ap + kk * 32);
    long gxn_p = gxp + gxstep;                 // t=511 strays inside ws (harmless)
    unsigned g2r = ld_g16(gx + gxn_p);
    unsigned g2z = ld_g16(gx + gxn_p + 1024);
    unsigned g2n = ld_g16(gx + gxn_p + 2048);
    asm volatile("s_waitcnt vmcnt(3)" ::: "memory");
    __builtin_amdgcn_sched_barrier(0);         // rule #18: fence MFMA behind wait

    // ---- 24 MFMAs: 3 gate chains over this wave's K-quarter
    f32x4 aR = {0.f,0.f,0.f,0.f}, aZ = {0.f,0.f,0.f,0.f}, aN = {0.f,0.f,0.f,0.f};
    #pragma unroll
    for (int kk = 0; kk < 8; ++kk) {
      aR = __builtin_amdgcn_mfma_f32_16x16x32_bf16(av[kk], wr[kk], aR, 0, 0, 0);
      aZ = __builtin_amdgcn_mfma_f32_16x16x32_bf16(av[kk], wz[kk], aZ, 0, 0, 0);
      aN = __builtin_amdgcn_mfma_f32_16x16x32_bf16(av[kk], wn[kk], aN, 0, 0, 0);
    }
    float* myl = lds + (size_t)(w2 * 64 + l) * 13;
    #pragma unroll
    for (int j = 0; j < 4; ++j) { myl[j] = aR[j]; myl[4 + j] = aZ[j]; myl[8 + j] = aN[j]; }
    __syncthreads();

    // ---- finish: combine 4 K-quarter partials, gate math (uses PREVIOUS
    // iteration's gx regs — landed since last vmcnt(0)), publish
    float ghr = 0.f, ghz = 0.f, ghn = 0.f;
    #pragma unroll
    for (int k2 = 0; k2 < 4; ++k2) {
      const float* pl = lds + (size_t)((k2 * 2 + chf) * 64 + lf) * 13;
      ghr += pl[jj]; ghz += pl[4 + jj]; ghn += pl[8 + jj];
    }
    float rgt = 1.f / (1.f + __expf(-(b2f((u16)gcr) + ghr + bhr)));
    float zgt = 1.f / (1.f + __expf(-(b2f((u16)gcz) + ghz + bhz)));
    float ngt = tanhf(b2f((u16)gcn) + rgt * (ghn + bhn));
    hp = (1.f - zgt) * ngt + zgt * hp;
    st_cc2(hb_out + hoff, f2b(hp));
    if (y_b) st_y16(y_b + yp, f2b(hp));
    else     st_y32(y_f + yp, hp);

    // ---- drain publish+y (+gx, already landed); rotate gx regs; stamp
    asm volatile("s_waitcnt vmcnt(0)" ::: "memory");
    gcr = g2r; gcz = g2z; gcn = g2n; gxp = gxn_p; yp += ystep;

    __syncthreads();                           // all waves' drains certified
    if (tid == 0) st_cc4(slots + m, (unsigned)(t + 2));
  }
}

// ---------------------------------------------------------------- launch
extern "C" void kernel_launch(void* const* d_in, const int* in_sizes, int n_in,
                              void* d_out, int out_size, void* d_ws, size_t ws_size,
                              hipStream_t stream) {
  (void)in_sizes; (void)n_in; (void)out_size; (void)ws_size;
  const float* x     = (const float*)d_in[0];   // [512,64,1024]
  const float* h0    = (const float*)d_in[1];   // [6,64,1024]
  const float* w_ih0 = (const float*)d_in[2];   // [2,3072,1024]
  const float* w_ih  = (const float*)d_in[3];   // [2,2,3072,2048]
  const float* w_hh  = (const float*)d_in[4];   // [3,2,3072,1024]
  const float* b_ih  = (const float*)d_in[5];   // [3,2,3072]
  const float* b_hh  = (const float*)d_in[6];   // [3,2,3072]
  float* out = (float*)d_out;                   // [512,64,2048]

  char* p = (char*)d_ws;
  u16* wA    = (u16*)p; p += (size_t)32768 * 2048 * 2;       // layer input bf16
  u16* wGx   = (u16*)p; p += (size_t)32768 * 6144 * 2;       // gate preacts bf16
  u16* wWih0 = (u16*)p; p += (size_t)6144 * 1024 * 2;
  u16* wWih  = (u16*)p; p += (size_t)2 * 6144 * 2048 * 2;
  u16* wWhh  = (u16*)p; p += (size_t)6 * 3072 * 1024 * 2;
  u16* wHb0  = (u16*)p; p += (size_t)2 * 64 * 1024 * 2;
  u16* wHb1  = (u16*)p; p += (size_t)2 * 64 * 1024 * 2;
  unsigned* wBar = (unsigned*)p; p += 4096 * 4;

  cvt_f32_bf16<<<2048, 256, 0, stream>>>(x,     wA,    (long)33554432);
  cvt_f32_bf16<<<2048, 256, 0, stream>>>(w_ih0, wWih0, (long)6291456);
  cvt_f32_bf16<<<2048, 256, 0, stream>>>(w_ih,  wWih,  (long)25165824);
  cvt_f32_bf16<<<2048, 256, 0, stream>>>(w_hh,  wWhh,  (long)18874368);

  for (int layer = 0; layer < 3; ++layer) {
    int K = (layer == 0) ? 1024 : 2048;
    const u16* Wg = (layer == 0) ? wWih0 : (wWih + (size_t)(layer - 1) * 6144 * 2048);
    gemm_bt_bias<<<dim3(48, 256), 256, 0, stream>>>(wA, Wg, b_ih + (size_t)layer * 6144, wGx, K);

    hipMemsetAsync(wBar, 0, 4096 * 4, stream);

    const u16* Whh_l   = wWhh + (size_t)layer * 2 * 3072 * 1024;
    const float* bhh_l = b_hh + (size_t)layer * 6144;
    const float* h0_l  = h0 + (size_t)layer * 131072;
    u16*   yb = (layer < 2) ? wA : nullptr;
    float* yf = (layer < 2) ? nullptr : out;
    gru_layer<<<256, 512, 0, stream>>>(wHb0, wHb1, Whh_l, bhh_l, wGx, yb, yf, h0_l, wBar);
  }
}

// Round 15
// 8454.063 us; speedup vs baseline: 2.1689x; 1.4479x over previous
//
#include <hip/hip_runtime.h>
#include <stdint.h>

typedef uint16_t u16;
typedef __attribute__((ext_vector_type(8))) short bf16x8;   // 8 bf16 in 4 VGPRs
typedef __attribute__((ext_vector_type(4))) float f32x4;
typedef __attribute__((ext_vector_type(4))) unsigned u32x4;

#define DEVI __device__ __forceinline__

DEVI u16 f2b(float f) {                       // f32 -> bf16 RNE
  uint32_t u = __float_as_uint(f);
  uint32_t r = (u + 0x7fffu + ((u >> 16) & 1u)) >> 16;
  return (u16)r;
}
DEVI float b2f(u16 h) { return __uint_as_float(((uint32_t)h) << 16); }

typedef const __attribute__((address_space(1))) uint32_t* gptr_t;
typedef __attribute__((address_space(3))) uint32_t* lptr_t;
DEVI void gload_lds16(const void* g, void* l) {
  __builtin_amdgcn_global_load_lds((gptr_t)g, (lptr_t)l, 16, 0, 0);
}

// L3-coherent accessors for cross-XCD exchange. PROVEN (R3/R4/R8/R9).
DEVI bf16x8 ld_cc16(const u16* p) {
  bf16x8 r;
  asm volatile("global_load_dwordx4 %0, %1, off sc0 sc1" : "=v"(r) : "v"(p));
  return r;   // caller must s_waitcnt vmcnt(0) + sched_barrier before use
}
DEVI void st_cc2(u16* p, u16 v) {
  uint32_t d = v;
  asm volatile("global_store_short %0, %1, off sc0 sc1" :: "v"(p), "v"(d) : "memory");
}
DEVI void st_cc4(unsigned* p, unsigned v) {
  asm volatile("global_store_dword %0, %1, off sc0 sc1" :: "v"(p), "v"(v) : "memory");
}
DEVI void st_y16(u16* p, u16 v) {
  uint32_t d = v;
  asm volatile("global_store_short %0, %1, off" :: "v"(p), "v"(d) : "memory");
}
DEVI void st_y32(float* p, float v) {
  asm volatile("global_store_dword %0, %1, off" :: "v"(p), "v"(v) : "memory");
}

// ---------------------------------------------------------------- converts
__global__ void cvt_f32_bf16(const float* __restrict__ in, u16* __restrict__ out, long n) {
  long i = ((long)blockIdx.x * blockDim.x + threadIdx.x) * 4;
  long stride = (long)gridDim.x * blockDim.x * 4;
  for (; i < n; i += stride) {
    float4 v = *(const float4*)(in + i);
    ushort4 o;
    o.x = f2b(v.x); o.y = f2b(v.y); o.z = f2b(v.z); o.w = f2b(v.w);
    *(ushort4*)(out + i) = o;
  }
}

// ---------------------------------------------------------------- GEMM 256x256, 8-phase
// C[m,n] = sum_k A[m,k]*W[n,k] + bias[n]; A:[M,K], W:[N,K] bf16 (B^T layout).
// Tile 256x256, BK=64, 2 K-tiles/iter, 512 thr = 8 waves (2M x 4N), each wave
// 128x64 out (acc[8][4] f32x4). LDS 128KB: As/Bs double-buffered 256x64 bf16,
// XOR-swizzled 16B slots (proven staging pattern). Per phase: ds_reads + one
// half-tile stage + barrier + setprio(1) 16xMFMA setprio(0) + barrier.
// vmcnt(0)+barrier at each K-tile top protects the buffer swap.
__global__ __launch_bounds__(512, 2) void gemm256(
    const u16* __restrict__ A, const u16* __restrict__ W,
    const float* __restrict__ bias, u16* __restrict__ C, int K) {
  constexpr int NLD = 6144;
  __shared__ u16 As[2][16384];   // [buf][256 rows x 64 cols]
  __shared__ u16 Bs[2][16384];
  const int t = threadIdx.x;
  const int l = t & 63, w = t >> 6;
  const int lr = l & 15, lk = l >> 4;
  const int wm = w >> 2, wn = w & 3;           // wave tile: rows wm*128, cols wn*64
  const long bm = (long)blockIdx.y * 256;
  const long bn = (long)blockIdx.x * 256;

  f32x4 acc[8][4] = {};

  // helper: stage one 128-row half (16KB) via 2 x global_load_lds per thread
  auto stage_half = [&](const u16* gsrc, char* ldst) {
    #pragma unroll
    for (int i = 0; i < 2; ++i) {
      int slotid = i * 512 + t;
      int r = slotid >> 3, s = slotid & 7;
      gload_lds16(gsrc + (long)r * K + ((s ^ (r & 7)) * 8),
                  ldst + i * 8192 + w * 1024);
    }
  };

  // prologue: stage K-tile 0 into buf 0 (4 halves); drained at iter-0 top
  stage_half(A + bm * K, (char*)As[0]);
  stage_half(A + (bm + 128) * K, (char*)As[0] + 16384);
  stage_half(W + bn * K, (char*)Bs[0]);
  stage_half(W + (bn + 128) * K, (char*)Bs[0] + 16384);

  const int NI = K >> 7;                       // 128 K per iter
  for (int i = 0; i < NI; ++i) {
    #pragma unroll
    for (int kt = 0; kt < 2; ++kt) {
      // buffer-swap protection: all stages into buf[kt] drained, all waves here
      asm volatile("s_waitcnt vmcnt(0)" ::: "memory");
      __builtin_amdgcn_s_barrier();

      const int rb = kt;                       // read buffer for this K-tile
      const int sbuf = kt ^ 1;                 // stage target buffer
      const long k0s = (long)(2 * i + 1 + kt) * 64;  // staged K-tile offset

      #pragma unroll
      for (int mh = 0; mh < 2; ++mh) {
        // A-frags for this m-half (8 ds_read_b128), reused across both nh
        bf16x8 af[4][2];
        #pragma unroll
        for (int m4 = 0; m4 < 4; ++m4) {
          int row = wm * 128 + (mh * 4 + m4) * 16 + lr;
          #pragma unroll
          for (int kk = 0; kk < 2; ++kk) {
            int sl = (kk * 4 + lk) ^ (row & 7);
            af[m4][kk] = *(const bf16x8*)((const char*)As[rb] + row * 128 + sl * 16);
          }
        }
        #pragma unroll
        for (int nh = 0; nh < 2; ++nh) {
          // B-frags (4 ds_read_b128)
          bf16x8 bfr[2][2];
          #pragma unroll
          for (int n2 = 0; n2 < 2; ++n2) {
            int row = wn * 64 + (nh * 2 + n2) * 16 + lr;
            #pragma unroll
            for (int kk = 0; kk < 2; ++kk) {
              int sl = (kk * 4 + lk) ^ (row & 7);
              bfr[n2][kk] = *(const bf16x8*)((const char*)Bs[rb] + row * 128 + sl * 16);
            }
          }
          // stage one half-tile of K-tile (2i+1+kt) into buf sbuf:
          // mh=0 -> A half nh; mh=1 -> B half nh
          if (mh == 0) stage_half(A + (bm + nh * 128) * K + k0s, (char*)As[sbuf] + nh * 16384);
          else         stage_half(W + (bn + nh * 128) * K + k0s, (char*)Bs[sbuf] + nh * 16384);

          __builtin_amdgcn_s_barrier();
          __builtin_amdgcn_s_setprio(1);
          #pragma unroll
          for (int m4 = 0; m4 < 4; ++m4)
            #pragma unroll
            for (int n2 = 0; n2 < 2; ++n2)
              #pragma unroll
              for (int kk = 0; kk < 2; ++kk)
                acc[mh * 4 + m4][nh * 2 + n2] = __builtin_amdgcn_mfma_f32_16x16x32_bf16(
                    af[m4][kk], bfr[n2][kk], acc[mh * 4 + m4][nh * 2 + n2], 0, 0, 0);
          __builtin_amdgcn_s_setprio(0);
          __builtin_amdgcn_s_barrier();
        }
      }
    }
  }

  // epilogue: bias + bf16 store (C/D: row=(l>>4)*4+j, col=l&15 — m89-verified)
  #pragma unroll
  for (int ni = 0; ni < 4; ++ni) {
    long col = bn + wn * 64 + ni * 16 + lr;
    float bv = bias[col];
    #pragma unroll
    for (int mi = 0; mi < 8; ++mi) {
      #pragma unroll
      for (int j = 0; j < 4; ++j) {
        long row = bm + wm * 128 + mi * 16 + lk * 4 + j;
        C[row * NLD + col] = f2b(acc[mi][ni][j] + bv);
      }
    }
  }
}

// ---------------------------------------------------------------- slot barrier (PROVEN R9)
// Store-only (no RMW): WG tid0 stores its monotone stamp (sc0sc1 -> L3).
// ALL waves poll the domain's 32 slots (8 lanes x dwordx4) until >= target.
DEVI void poll_slots(const unsigned* slots, unsigned tgt, int l) {
  const unsigned* pp = slots + (l & 7) * 4;
  for (;;) {
    u32x4 v;
    asm volatile("global_load_dwordx4 %0, %1, off sc0 sc1" : "=v"(v) : "v"(pp));
    asm volatile("s_waitcnt vmcnt(0)" ::: "memory");
    int ok = (l < 8) ? (v.x >= tgt && v.y >= tgt && v.z >= tgt && v.w >= tgt) : 1;
    if (__all(ok)) break;
    __builtin_amdgcn_s_sleep(1);
  }
}

// ---------------------------------------------------------------- persistent GRU layer
// BYTE-IDENTICAL to R9 (proven 2.12 ms/layer). 256 WGs x 512 thr; WG: domain
// dmn=bid&7 (dir=dmn>>2, rg=dmn&3 -> 16 rows), m=bid>>3 (32 cols). Domain =
// 32 WGs exchanging h via sc0sc1. Store-only slot barrier, all-wave polling.
// Weights parked in 96 AGPRs, builtin MFMA.
__global__ __launch_bounds__(512, 2) void gru_layer(
    u16* __restrict__ hbA, u16* __restrict__ hbB,
    const u16* __restrict__ Whh,   // [2,3072,1024] bf16 (this layer)
    const float* __restrict__ bhh, // [2,3072] f32
    const u16* __restrict__ gx,    // [32768,6144] bf16
    u16* __restrict__ y_b, float* __restrict__ y_f,   // one non-null
    const float* __restrict__ h0l, // [2,64,1024] f32 (this layer)
    unsigned* bar) {
  __shared__ float lds[8 * 64 * 13];

  const int bid = blockIdx.x;
  const int dmn = bid & 7, m = bid >> 3;
  const int dir = dmn >> 2, rg = dmn & 3;
  const int tid = threadIdx.x;
  const int w2 = tid >> 6, l = tid & 63;
  const int lr = l & 15, lk = l >> 4;
  const int ch = w2 & 1, kh = w2 >> 1;

  unsigned* slots = bar + dmn * 64;           // 32 stamps per domain, 256B apart

  // ---- finish-lane constants + h0 init
  const int fcol5 = tid & 31, frow = tid >> 5;      // 32 cols x 16 rows
  const int colg = m * 32 + fcol5;
  const int growd = rg * 16 + frow;
  const float bhr = bhh[dir * 3072 + colg];
  const float bhz = bhh[dir * 3072 + 1024 + colg];
  const float bhn = bhh[dir * 3072 + 2048 + colg];
  const size_t hoff = (size_t)(dir * 64 + growd) * 1024 + colg;
  float hp = h0l[hoff];
  st_cc2(hbA + hoff, f2b(hp));                // visible at L3 to all XCDs

  // ---- weights -> AGPRs (3 gates x 16 cols x 256 K per wave = 96 AGPRs)
  const u16* wb = Whh + ((size_t)(dir * 3072 + m * 32 + ch * 16 + lr)) * 1024 + kh * 256 + lk * 8;
  asm volatile("" : "+v"(wb));
  bf16x8 wr[8], wz[8], wn[8];
  #pragma unroll
  for (int kk = 0; kk < 8; ++kk) {
    wr[kk] = *(const bf16x8*)(wb + kk * 32);
    wz[kk] = *(const bf16x8*)(wb + 1024 * 1024 + kk * 32);
    wn[kk] = *(const bf16x8*)(wb + 2048 * 1024 + kk * 32);
  }
  #pragma unroll
  for (int kk = 0; kk < 8; ++kk)
    asm volatile("" : "+a"(wr[kk]), "+a"(wz[kk]), "+a"(wn[kk]));

  // ---- loop state
  const int tt0 = dir ? 511 : 0;
  long gxp = (long)(tt0 * 64 + growd) * 6144 + (long)dir * 3072 + colg;
  const long gxstep = dir ? -(64 * 6144) : (64 * 6144);
  long yp = (long)(tt0 * 64 + growd) * 2048 + (long)dir * 1024 + colg;
  const long ystep = dir ? -(64 * 2048) : (64 * 2048);

  const u16* apA = hbA + (size_t)(dir * 64 + rg * 16 + lr) * 1024 + kh * 256 + lk * 8;
  const u16* apB = hbB + (size_t)(dir * 64 + rg * 16 + lr) * 1024 + kh * 256 + lk * 8;

  const int lf = ((frow >> 2) << 4) | (fcol5 & 15);  // source lane in compute wave
  const int jj = frow & 3;                           // acc reg index
  const int chf = fcol5 >> 4;                        // source col-half

  // gx prefetch for t=0 (plain cached)
  u16 gcr = gx[gxp], gcz = gx[gxp + 1024], gcn = gx[gxp + 2048];

  asm volatile("s_waitcnt vmcnt(0)" ::: "memory");   // h0 publish drained to L3
  __syncthreads();
  if (tid == 0) st_cc4(slots + m, 1u);
  poll_slots(slots, 1u, l);

  for (int t = 0; t < 512; ++t) {
    const u16* ap = (t & 1) ? apB : apA;
    u16* hb_out = (t & 1) ? hbA : hbB;

    // ---- h loads for this wave's K-quarter (8 x dwordx4, sc0sc1)
    bf16x8 av[8];
    #pragma unroll
    for (int kk = 0; kk < 8; ++kk) av[kk] = ld_cc16(ap + kk * 32);
    asm volatile("s_waitcnt vmcnt(0)" ::: "memory");
    __builtin_amdgcn_sched_barrier(0);

    // ---- 24 MFMAs: 3 gate chains over this wave's K-quarter
    f32x4 aR = {0.f,0.f,0.f,0.f}, aZ = {0.f,0.f,0.f,0.f}, aN = {0.f,0.f,0.f,0.f};
    #pragma unroll
    for (int kk = 0; kk < 8; ++kk) {
      aR = __builtin_amdgcn_mfma_f32_16x16x32_bf16(av[kk], wr[kk], aR, 0, 0, 0);
      aZ = __builtin_amdgcn_mfma_f32_16x16x32_bf16(av[kk], wz[kk], aZ, 0, 0, 0);
      aN = __builtin_amdgcn_mfma_f32_16x16x32_bf16(av[kk], wn[kk], aN, 0, 0, 0);
    }
    float* myl = lds + (size_t)(w2 * 64 + l) * 13;
    #pragma unroll
    for (int j = 0; j < 4; ++j) { myl[j] = aR[j]; myl[4 + j] = aZ[j]; myl[8 + j] = aN[j]; }
    __syncthreads();

    // ---- finish: combine 4 K-quarter partials, prefetch next gx, gate math
    float ghr = 0.f, ghz = 0.f, ghn = 0.f;
    #pragma unroll
    for (int k2 = 0; k2 < 4; ++k2) {
      const float* pl = lds + (size_t)((k2 * 2 + chf) * 64 + lf) * 13;
      ghr += pl[jj]; ghz += pl[4 + jj]; ghn += pl[8 + jj];
    }
    long gxn_p = gxp + gxstep;                 // t=511 prefetch strays inside ws (harmless)
    u16 g2r = gx[gxn_p], g2z = gx[gxn_p + 1024], g2n = gx[gxn_p + 2048];

    float rgt = 1.f / (1.f + __expf(-(b2f(gcr) + ghr + bhr)));
    float zgt = 1.f / (1.f + __expf(-(b2f(gcz) + ghz + bhz)));
    float ngt = tanhf(b2f(gcn) + rgt * (ghn + bhn));
    hp = (1.f - zgt) * ngt + zgt * hp;
    st_cc2(hb_out + hoff, f2b(hp));
    if (y_b) st_y16(y_b + yp, f2b(hp));
    else     st_y32(y_f + yp, hp);

    asm volatile("s_waitcnt vmcnt(0)" ::: "memory");  // publish + y + g2 drained
    gcr = g2r; gcz = g2z; gcn = g2n; gxp = gxn_p; yp += ystep;

    __syncthreads();                                   // all waves drained
    if (tid == 0) st_cc4(slots + m, (unsigned)(t + 2));
    poll_slots(slots, (unsigned)(t + 2), l);           // all waves self-release
  }
}

// ---------------------------------------------------------------- launch
extern "C" void kernel_launch(void* const* d_in, const int* in_sizes, int n_in,
                              void* d_out, int out_size, void* d_ws, size_t ws_size,
                              hipStream_t stream) {
  (void)in_sizes; (void)n_in; (void)out_size; (void)ws_size;
  const float* x     = (const float*)d_in[0];   // [512,64,1024]
  const float* h0    = (const float*)d_in[1];   // [6,64,1024]
  const float* w_ih0 = (const float*)d_in[2];   // [2,3072,1024]
  const float* w_ih  = (const float*)d_in[3];   // [2,2,3072,2048]
  const float* w_hh  = (const float*)d_in[4];   // [3,2,3072,1024]
  const float* b_ih  = (const float*)d_in[5];   // [3,2,3072]
  const float* b_hh  = (const float*)d_in[6];   // [3,2,3072]
  float* out = (float*)d_out;                   // [512,64,2048]

  char* p = (char*)d_ws;
  u16* wA    = (u16*)p; p += (size_t)32768 * 2048 * 2;       // layer input bf16
  u16* wGx   = (u16*)p; p += (size_t)32768 * 6144 * 2;       // gate preacts bf16
  u16* wWih0 = (u16*)p; p += (size_t)6144 * 1024 * 2;
  u16* wWih  = (u16*)p; p += (size_t)2 * 6144 * 2048 * 2;
  u16* wWhh  = (u16*)p; p += (size_t)6 * 3072 * 1024 * 2;
  u16* wHb0  = (u16*)p; p += (size_t)2 * 64 * 1024 * 2;
  u16* wHb1  = (u16*)p; p += (size_t)2 * 64 * 1024 * 2;
  unsigned* wBar = (unsigned*)p; p += 4096 * 4;

  cvt_f32_bf16<<<2048, 256, 0, stream>>>(x,     wA,    (long)33554432);
  cvt_f32_bf16<<<2048, 256, 0, stream>>>(w_ih0, wWih0, (long)6291456);
  cvt_f32_bf16<<<2048, 256, 0, stream>>>(w_ih,  wWih,  (long)25165824);
  cvt_f32_bf16<<<2048, 256, 0, stream>>>(w_hh,  wWhh,  (long)18874368);

  for (int layer = 0; layer < 3; ++layer) {
    int K = (layer == 0) ? 1024 : 2048;
    const u16* Wg = (layer == 0) ? wWih0 : (wWih + (size_t)(layer - 1) * 6144 * 2048);
    gemm256<<<dim3(24, 128), 512, 0, stream>>>(wA, Wg, b_ih + (size_t)layer * 6144, wGx, K);

    hipMemsetAsync(wBar, 0, 4096 * 4, stream);

    const u16* Whh_l   = wWhh + (size_t)layer * 2 * 3072 * 1024;
    const float* bhh_l = b_hh + (size_t)layer * 6144;
    const float* h0_l  = h0 + (size_t)layer * 131072;
    u16*   yb = (layer < 2) ? wA : nullptr;
    float* yf = (layer < 2) ? nullptr : out;
    gru_layer<<<256, 512, 0, stream>>>(wHb0, wHb1, Whh_l, bhh_l, wGx, yb, yf, h0_l, wBar);
  }
}